// Round 2
// baseline (652.476 us; speedup 1.0000x reference)
//
#include <hip/hip_runtime.h>
#include <hip/hip_bf16.h>

#define N_NODES 100000
#define N_EDGES 1600000
#define NSLICE 8
#define SLICE_N (N_NODES / NSLICE)      // 12500
#define FILL_CHUNKS 256
#define CHUNK_E (N_EDGES / FILL_CHUNKS) // 6250

typedef unsigned short ushort_t;
typedef unsigned int uint_t;
typedef __bf16 bf16x8 __attribute__((ext_vector_type(8)));
typedef float f32x4 __attribute__((ext_vector_type(4)));

__device__ __forceinline__ float bf2f(uint_t u) {
    union { uint_t i; float f; } v; v.i = u << 16; return v.f;
}
__device__ __forceinline__ ushort_t f2bf(float f) {
    uint_t x = __float_as_uint(f);
    uint_t r = (x + 0x7fffu + ((x >> 16) & 1u)) >> 16;
    return (ushort_t)r;
}

// ---------------- CSR build (XCD-sliced: slice = blockIdx&7 keeps each dst
// range's deg/cursor/col window resident in one XCD's L2) ----------------

__global__ void k_hist(const int* __restrict__ dst, int* __restrict__ deg) {
    int slice = blockIdx.x & (NSLICE - 1);
    int chunk = blockIdx.x >> 3;
    int lo = slice * SLICE_N, hi = lo + SLICE_N;
    int base = chunk * CHUNK_E;
    for (int e = base + threadIdx.x; e < base + CHUNK_E; e += 256) {
        int d = dst[e];
        if (d >= lo && d < hi) atomicAdd(&deg[d], 1);
    }
}

__global__ void k_block_reduce(const int* __restrict__ deg, int* __restrict__ bsums) {
    __shared__ int sm[256];
    int t = threadIdx.x;
    int n = blockIdx.x * 256 + t;
    int v = (n < N_NODES) ? deg[n] : 0;
    sm[t] = v; __syncthreads();
    for (int off = 128; off > 0; off >>= 1) {
        if (t < off) sm[t] += sm[t + off];
        __syncthreads();
    }
    if (t == 0) bsums[blockIdx.x] = sm[0];
}

__global__ void k_top_scan(int* __restrict__ bsums, int nb) {
    __shared__ int sm[512];
    int t = threadIdx.x;
    int v = (t < nb) ? bsums[t] : 0;
    sm[t] = v; __syncthreads();
    for (int off = 1; off < 512; off <<= 1) {
        int x = (t >= off) ? sm[t - off] : 0;
        __syncthreads();
        sm[t] += x;
        __syncthreads();
    }
    if (t < nb) bsums[t] = sm[t] - v;   // exclusive
}

__global__ void k_scan_final(const int* __restrict__ deg, const int* __restrict__ bsums,
                             int* __restrict__ row_start, int* __restrict__ cursor) {
    __shared__ int sm[256];
    int t = threadIdx.x;
    int n = blockIdx.x * 256 + t;
    int v = (n < N_NODES) ? deg[n] : 0;
    sm[t] = v; __syncthreads();
    for (int off = 1; off < 256; off <<= 1) {
        int x = (t >= off) ? sm[t - off] : 0;
        __syncthreads();
        sm[t] += x;
        __syncthreads();
    }
    int excl = bsums[blockIdx.x] + sm[t] - v;
    if (n < N_NODES) { row_start[n] = excl; cursor[n] = excl; }
    if (n == 0) row_start[N_NODES] = N_EDGES;
}

__global__ void k_fill(const int* __restrict__ src, const int* __restrict__ dst,
                       int* __restrict__ cursor, int* __restrict__ col) {
    int slice = blockIdx.x & (NSLICE - 1);
    int chunk = blockIdx.x >> 3;
    int lo = slice * SLICE_N, hi = lo + SLICE_N;
    int base = chunk * CHUNK_E;
    for (int e = base + threadIdx.x; e < base + CHUNK_E; e += 256) {
        int d = dst[e];
        if (d >= lo && d < hi) {
            int s = src[e];
            int p = atomicAdd(&cursor[d], 1);
            col[p] = s;
        }
    }
}

// ---------------- conversions ----------------

__global__ void k_cvt_x(const float* __restrict__ x, ushort_t* __restrict__ h) {
    int i = (blockIdx.x * 256 + threadIdx.x) * 4;   // N*128 == 12500*256*4 exactly
    float4 v = *(const float4*)(x + i);
    uint2 o;
    o.x = (uint_t)f2bf(v.x) | ((uint_t)f2bf(v.y) << 16);
    o.y = (uint_t)f2bf(v.z) | ((uint_t)f2bf(v.w) << 16);
    *(uint2*)(h + i) = o;
}

// Wt layout: [do][256] bf16, k-major (k rows 0..127 = W_self, 128..255 = W_neigh)
__global__ void k_cvt_w(const float* __restrict__ ws0, const float* __restrict__ wn0,
                        const float* __restrict__ ws1, const float* __restrict__ wn1,
                        const float* __restrict__ ws2, const float* __restrict__ wn2,
                        ushort_t* __restrict__ wt0, ushort_t* __restrict__ wt1,
                        ushort_t* __restrict__ wt2) {
    int idx = blockIdx.x * 256 + threadIdx.x;   // 0..81919 (320 blocks)
    const float *Ws, *Wn; ushort_t* Wt; int DO_; int local;
    if (idx < 32768)      { Ws = ws0; Wn = wn0; Wt = wt0; DO_ = 128; local = idx; }
    else if (idx < 65536) { Ws = ws1; Wn = wn1; Wt = wt1; DO_ = 128; local = idx - 32768; }
    else                  { Ws = ws2; Wn = wn2; Wt = wt2; DO_ = 64;  local = idx - 65536; }
    int n = local >> 8, k = local & 255;
    if (n < DO_) {
        float v = (k < 128) ? Ws[k * DO_ + n] : Wn[(k - 128) * DO_ + n];
        Wt[n * 256 + k] = f2bf(v);
    }
}

// ---------------- fused gather-mean + dual-GEMM + bias (+ReLU) ----------------
// Each wave gathers the 16 neighbor-mean rows it will itself consume as its
// MFMA A-operand (LDS tile is wave-private -> no __syncthreads needed).
// Weights are read from global (64KB, L2-broadcast) to keep LDS small (17KB)
// and occupancy high for the latency-bound gather phase.

template <int DOv, bool RELU, bool OUTF32>
__global__ __launch_bounds__(256, 4) void k_fused(const ushort_t* __restrict__ h,
                                                  const int* __restrict__ rs,
                                                  const int* __restrict__ col,
                                                  const ushort_t* __restrict__ wt,
                                                  const float* __restrict__ bias,
                                                  ushort_t* __restrict__ hout,
                                                  float* __restrict__ fout) {
    __shared__ ushort_t lds_hn[64][136];   // pitch 272B = 68 dw, 68%32==4 -> 2-way (free)
    const int t = threadIdx.x;
    const int wid = t >> 6, lane = t & 63;
    const int row0 = blockIdx.x * 64 + wid * 16;

    // ---- gather phase: 16 nodes per wave, lane = feature-pair ----
    for (int s = 0; s < 16; ++s) {
        int node = row0 + s;
        if (node >= N_NODES) break;           // wave-uniform
        int beg = rs[node], end = rs[node + 1];
        float a0 = 0.f, a1 = 0.f;
        int i = beg;
        for (; i + 8 <= end; i += 8) {
            uint_t v[8];
#pragma unroll
            for (int j = 0; j < 8; ++j) {
                int sn = col[i + j];          // wave-uniform -> s_load
                v[j] = *(const uint_t*)(h + (size_t)sn * 128 + lane * 2);
            }
#pragma unroll
            for (int j = 0; j < 8; ++j) {
                a0 += bf2f(v[j] & 0xffffu); a1 += bf2f(v[j] >> 16);
            }
        }
        int rem = end - i;                    // 0..7
        if (rem > 0) {
            int e7 = end - 1;
            uint_t v[8];
#pragma unroll
            for (int j = 0; j < 8; ++j) {
                int idx = i + j; if (idx > e7) idx = e7;
                int sn = col[idx];
                v[j] = *(const uint_t*)(h + (size_t)sn * 128 + lane * 2);
            }
#pragma unroll
            for (int j = 0; j < 8; ++j) {
                if (j < rem) { a0 += bf2f(v[j] & 0xffffu); a1 += bf2f(v[j] >> 16); }
            }
        }
        float inv = (end > beg) ? 1.0f / (float)(end - beg) : 0.f;
        uint_t o = (uint_t)f2bf(a0 * inv) | ((uint_t)f2bf(a1 * inv) << 16);
        *(uint_t*)(&lds_hn[wid * 16 + s][lane * 2]) = o;
    }

    // ---- GEMM phase: out[16 x DOv] = [h_self | h_neigh](16x256) @ Wt^T ----
    constexpr int NT = DOv / 16;
    int arow = row0 + (lane & 15);
    if (arow >= N_NODES) arow = N_NODES - 1;
    int hi = lane >> 4;   // 0..3

    f32x4 acc[NT];
#pragma unroll
    for (int n = 0; n < NT; n++) acc[n] = (f32x4){0.f, 0.f, 0.f, 0.f};

#pragma unroll
    for (int kk = 0; kk < 8; kk++) {
        bf16x8 a;
        if (kk < 4) a = *(const bf16x8*)(h + (size_t)arow * 128 + kk * 32 + hi * 8);
        else        a = *(const bf16x8*)(&lds_hn[wid * 16 + (lane & 15)][(kk - 4) * 32 + hi * 8]);
#pragma unroll
        for (int n = 0; n < NT; n++) {
            bf16x8 b = *(const bf16x8*)(wt + (size_t)(n * 16 + (lane & 15)) * 256 + kk * 32 + hi * 8);
            acc[n] = __builtin_amdgcn_mfma_f32_16x16x32_bf16(a, b, acc[n], 0, 0, 0);
        }
    }

#pragma unroll
    for (int n = 0; n < NT; n++) {
        int colc = n * 16 + (lane & 15);
        float bv = bias[colc];
#pragma unroll
        for (int j = 0; j < 4; j++) {
            int row = row0 + hi * 4 + j;
            if (row < N_NODES) {
                float v = acc[n][j] + bv;
                if (RELU) v = v > 0.f ? v : 0.f;
                if (OUTF32) fout[(size_t)row * DOv + colc] = v;
                else        hout[(size_t)row * 128 + colc] = f2bf(v);
            }
        }
    }
}

// ---------------- launch ----------------

extern "C" void kernel_launch(void* const* d_in, const int* in_sizes, int n_in,
                              void* d_out, int out_size, void* d_ws, size_t ws_size,
                              hipStream_t stream) {
    const float* x   = (const float*)d_in[0];
    const int*   src = (const int*)d_in[1];
    const int*   dst = (const int*)d_in[2];
    const float* ws0 = (const float*)d_in[3];
    const float* wn0 = (const float*)d_in[4];
    const float* b0  = (const float*)d_in[5];
    const float* ws1 = (const float*)d_in[6];
    const float* wn1 = (const float*)d_in[7];
    const float* b1  = (const float*)d_in[8];
    const float* ws2 = (const float*)d_in[9];
    const float* wn2 = (const float*)d_in[10];
    const float* b2  = (const float*)d_in[11];

    char* ws = (char*)d_ws;
    size_t o = 0;
    auto alloc = [&](size_t bytes) { size_t r = o; o = (o + bytes + 255) & ~(size_t)255; return r; };
    int* deg        = (int*)(ws + alloc((size_t)N_NODES * 4));
    int* row_start  = (int*)(ws + alloc((size_t)(N_NODES + 1) * 4));
    int* cursor     = (int*)(ws + alloc((size_t)N_NODES * 4));
    int* bsums      = (int*)(ws + alloc(512 * 4));
    int* col        = (int*)(ws + alloc((size_t)N_EDGES * 4));
    ushort_t* wt0   = (ushort_t*)(ws + alloc(128 * 256 * 2));
    ushort_t* wt1   = (ushort_t*)(ws + alloc(128 * 256 * 2));
    ushort_t* wt2   = (ushort_t*)(ws + alloc(64 * 256 * 2));
    ushort_t* hA    = (ushort_t*)(ws + alloc((size_t)N_NODES * 128 * 2));
    ushort_t* hB    = (ushort_t*)(ws + alloc((size_t)N_NODES * 128 * 2));
    (void)ws_size;

    const int NB_SCAN = (N_NODES + 255) / 256;   // 391
    const int CSR_GRID = FILL_CHUNKS * NSLICE;   // 2048

    hipMemsetAsync(deg, 0, (size_t)N_NODES * 4, stream);
    k_hist<<<CSR_GRID, 256, 0, stream>>>(dst, deg);
    k_block_reduce<<<NB_SCAN, 256, 0, stream>>>(deg, bsums);
    k_top_scan<<<1, 512, 0, stream>>>(bsums, NB_SCAN);
    k_scan_final<<<NB_SCAN, 256, 0, stream>>>(deg, bsums, row_start, cursor);
    k_fill<<<CSR_GRID, 256, 0, stream>>>(src, dst, cursor, col);

    k_cvt_x<<<(N_NODES * 128 / 4) / 256, 256, 0, stream>>>(x, hA);
    k_cvt_w<<<320, 256, 0, stream>>>(ws0, wn0, ws1, wn1, ws2, wn2, wt0, wt1, wt2);

    const int FUSED_GRID = (N_NODES + 63) / 64;  // 1563

    k_fused<128, true,  false><<<FUSED_GRID, 256, 0, stream>>>(hA, row_start, col, wt0, b0, hB, nullptr);
    k_fused<128, true,  false><<<FUSED_GRID, 256, 0, stream>>>(hB, row_start, col, wt1, b1, hA, nullptr);
    k_fused<64,  false, true ><<<FUSED_GRID, 256, 0, stream>>>(hA, row_start, col, wt2, b2, nullptr, (float*)d_out);
}